// Round 1
// baseline (569.441 us; speedup 1.0000x reference)
//
#include <hip/hip_runtime.h>
#include <stdint.h>

#define AS1 __attribute__((address_space(1)))
#define AS3 __attribute__((address_space(3)))

typedef float v4f __attribute__((ext_vector_type(4)));
typedef __bf16 v8bf __attribute__((ext_vector_type(8)));

static_assert(sizeof(v8bf) == 16, "v8bf must be 16B");

__device__ __forceinline__ unsigned short f2bf(float f) {
  unsigned int x = __float_as_uint(f);
  x += 0x7fffu + ((x >> 16) & 1u);
  return (unsigned short)(x >> 16);
}

__device__ __forceinline__ void async16(void* lds, const void* g) {
  __builtin_amdgcn_global_load_lds((const AS1 unsigned int*)g,
                                   (AS3 unsigned int*)lds, 16, 0, 0);
}

// ---------------- prep kernels ----------------

// M = 0.99*I - 0.001*(W_e + W_e^T); m3 = M^3  (64 floats)
__global__ void prep_m3_kernel(const float* __restrict__ We, float* __restrict__ m3) {
  __shared__ float Ms[64], M2[64];
  int t = threadIdx.x;        // 64 threads
  int i = t >> 3, j = t & 7;
  float wsym = We[i * 8 + j] + We[j * 8 + i];
  Ms[t] = (i == j ? 0.99f : 0.0f) - 0.001f * wsym;
  __syncthreads();
  float s = 0.f;
#pragma unroll
  for (int p = 0; p < 8; ++p) s += Ms[i * 8 + p] * Ms[p * 8 + j];
  M2[t] = s;
  __syncthreads();
  s = 0.f;
#pragma unroll
  for (int p = 0; p < 8; ++p) s += M2[i * 8 + p] * Ms[p * 8 + j];
  m3[t] = s;
}

// b_in'[n] = sum_p b_in[(n&~7)+p] * m3[p][n&7]   (16384 outputs)
__global__ void fold_bias_kernel(const float* __restrict__ b, const float* __restrict__ m3,
                                 float* __restrict__ bo) {
  int n = blockIdx.x * 256 + threadIdx.x;
  int j = n & 7, lo = n & ~7;
  float s = 0.f;
#pragma unroll
  for (int p = 0; p < 8; ++p) s += b[lo + p] * m3[p * 8 + j];
  bo[n] = s;
}

// f32 -> bf16 elementwise, 8 elems/thread
__global__ void cvt_bf16_kernel(const float* __restrict__ in, unsigned short* __restrict__ out) {
  int i = (blockIdx.x * 256 + threadIdx.x) * 8;
  float4 a = *(const float4*)(in + i);
  float4 b = *(const float4*)(in + i + 4);
  alignas(16) unsigned short r[8] = {f2bf(a.x), f2bf(a.y), f2bf(a.z), f2bf(a.w),
                                     f2bf(b.x), f2bf(b.y), f2bf(b.z), f2bf(b.w)};
  *(uint4*)(out + i) = *(const uint4*)r;
}

// Transpose (K x N f32, row-major) -> (N x K bf16, row-major), optionally folding
// M3 along n within 8-column groups: out[n][k] = sum_p in[k][(n&~7)+p]*m3[p][n&7]
template <bool FOLD>
__global__ __launch_bounds__(256) void transpose_cvt_kernel(
    const float* __restrict__ in, unsigned short* __restrict__ outT,
    int K, int N, const float* __restrict__ m3) {
  __shared__ float tile[64][65];
  __shared__ float m3s[64];
  const int t = threadIdx.x;
  const int k0 = blockIdx.x * 64, n0 = blockIdx.y * 64;
  if (FOLD && t < 64) m3s[t] = m3[t];
  {
    int row = t >> 2, ch = t & 3;
    const float* g = in + (size_t)(k0 + row) * N + n0 + ch * 16;
    float4 v0 = ((const float4*)g)[0];
    float4 v1 = ((const float4*)g)[1];
    float4 v2 = ((const float4*)g)[2];
    float4 v3 = ((const float4*)g)[3];
    float* d = &tile[row][ch * 16];
    d[0] = v0.x; d[1] = v0.y; d[2] = v0.z; d[3] = v0.w;
    d[4] = v1.x; d[5] = v1.y; d[6] = v1.z; d[7] = v1.w;
    d[8] = v2.x; d[9] = v2.y; d[10] = v2.z; d[11] = v2.w;
    d[12] = v3.x; d[13] = v3.y; d[14] = v3.z; d[15] = v3.w;
  }
  __syncthreads();
  const int nl = t >> 2, kch = t & 3;
  alignas(16) unsigned short r[16];
  if (FOLD) {
    const int j = nl & 7, lo = nl & 56;
    float mcol[8];
#pragma unroll
    for (int p = 0; p < 8; ++p) mcol[p] = m3s[p * 8 + j];
#pragma unroll
    for (int i = 0; i < 16; ++i) {
      int kk = kch * 16 + i;
      float s = 0.f;
#pragma unroll
      for (int p = 0; p < 8; ++p) s += tile[kk][lo + p] * mcol[p];
      r[i] = f2bf(s);
    }
  } else {
#pragma unroll
    for (int i = 0; i < 16; ++i) r[i] = f2bf(tile[kch * 16 + i][nl]);
  }
  uint4* dst = (uint4*)(outT + (size_t)(n0 + nl) * K + k0 + kch * 16);
  dst[0] = ((const uint4*)r)[0];
  dst[1] = ((const uint4*)r)[1];
}

// ---------------- GEMM (m97-style 128-tile, bf16 MFMA 16x16x32) ----------------
// C[M][N] = A[M][K] @ BT[N][K]^T + bias[N]
// Block: 256 threads = 4 waves in 2x2; wave tile = (MF*16) x (NF*16).
template <int MF, int NF, bool OUT_BF16>
__global__ __launch_bounds__(256, 2) void gemm_kernel(
    const unsigned short* __restrict__ A, const unsigned short* __restrict__ BT,
    const float* __restrict__ bias, void* __restrict__ Cout,
    int M, int N, int K) {
  constexpr int BM = 32 * MF, BN = 32 * NF;
  constexpr int ISS = (BM + BN) / 64;  // 4KB staging issues per K-step
  __shared__ unsigned short lds[(BM + BN) * 32];

  const int t = threadIdx.x;
  const int bn = blockIdx.x, bm = blockIdx.y;
  const int m0 = bm * BM, n0 = bn * BN;
  const int lane = t & 63;
  const int w = t >> 6;
  const int wr = w >> 1, wc = w & 1;
  const int r16 = lane & 15, kc = lane >> 4;

  v4f acc[MF][NF];
#pragma unroll
  for (int m = 0; m < MF; ++m)
#pragma unroll
    for (int n = 0; n < NF; ++n) acc[m][n] = (v4f){0.f, 0.f, 0.f, 0.f};

  for (int k0 = 0; k0 < K; k0 += 32) {
#pragma unroll
    for (int i = 0; i < ISS; ++i) {
      int slot = i * 256 + t;          // 16-byte slot index
      int row = slot >> 2, ch = slot & 3;
      const unsigned short* g =
          (row < BM) ? (A + (size_t)(m0 + row) * K + k0 + ch * 8)
                     : (BT + (size_t)(n0 + row - BM) * K + k0 + ch * 8);
      async16(&lds[slot * 8], g);
    }
    __syncthreads();   // compiler drains vmcnt before s_barrier

    v8bf af[MF], bfr[NF];
#pragma unroll
    for (int m = 0; m < MF; ++m)
      af[m] = *(const v8bf*)&lds[(wr * MF * 16 + m * 16 + r16) * 32 + kc * 8];
#pragma unroll
    for (int n = 0; n < NF; ++n)
      bfr[n] = *(const v8bf*)&lds[(BM + wc * NF * 16 + n * 16 + r16) * 32 + kc * 8];
#pragma unroll
    for (int m = 0; m < MF; ++m)
#pragma unroll
      for (int n = 0; n < NF; ++n)
        acc[m][n] = __builtin_amdgcn_mfma_f32_16x16x32_bf16(af[m], bfr[n], acc[m][n], 0, 0, 0);
    __syncthreads();   // protect LDS from next iteration's staging
  }

#pragma unroll
  for (int m = 0; m < MF; ++m) {
    int grow = m0 + wr * MF * 16 + m * 16 + kc * 4;
#pragma unroll
    for (int n = 0; n < NF; ++n) {
      int gcol = n0 + wc * NF * 16 + n * 16 + r16;
      float bv = bias[gcol];
#pragma unroll
      for (int j = 0; j < 4; ++j) {
        float v = acc[m][n][j] + bv;
        size_t idx = (size_t)(grow + j) * N + gcol;
        if (OUT_BF16)
          ((unsigned short*)Cout)[idx] = f2bf(v);
        else
          ((float*)Cout)[idx] = v;
      }
    }
  }
}

// ---------------- launch ----------------

extern "C" void kernel_launch(void* const* d_in, const int* in_sizes, int n_in,
                              void* d_out, int out_size, void* d_ws, size_t ws_size,
                              hipStream_t stream) {
  const float* x     = (const float*)d_in[0];   // 1024 x 4096
  const float* W_in  = (const float*)d_in[1];   // 4096 x 16384
  const float* b_in  = (const float*)d_in[2];   // 16384
  const float* W_e   = (const float*)d_in[3];   // 8 x 8
  const float* W_out = (const float*)d_in[4];   // 16384 x 2048
  const float* b_out = (const float*)d_in[5];   // 2048
  float* out = (float*)d_out;                   // 1024 x 2048 f32

  char* ws = (char*)d_ws;
  const size_t OFF_M3   = 0;                    // 256 B
  const size_t OFF_BIAS = 4096;                 // 64 KB
  const size_t OFF_X    = 1ull << 20;           // 8 MB   (x bf16)
  const size_t OFF_H    = 10ull << 20;          // 32 MB  (h bf16)
  const size_t OFF_W    = 48ull << 20;          // 128 MB (W1T then W2T, reused)
  float* m3            = (float*)(ws + OFF_M3);
  float* biasf         = (float*)(ws + OFF_BIAS);
  unsigned short* xb   = (unsigned short*)(ws + OFF_X);
  unsigned short* h    = (unsigned short*)(ws + OFF_H);
  unsigned short* wT   = (unsigned short*)(ws + OFF_W);

  prep_m3_kernel<<<1, 64, 0, stream>>>(W_e, m3);
  fold_bias_kernel<<<64, 256, 0, stream>>>(b_in, m3, biasf);
  cvt_bf16_kernel<<<2048, 256, 0, stream>>>(x, xb);  // 1024*4096 / (256*8)

  // W_in (4096 x 16384) -> fold M3 + transpose -> W1T (16384 x 4096) bf16
  transpose_cvt_kernel<true><<<dim3(4096 / 64, 16384 / 64), 256, 0, stream>>>(
      W_in, wT, 4096, 16384, m3);

  // h = x @ W1T^T + b_in'   (1024 x 16384, bf16 out)
  gemm_kernel<4, 4, true><<<dim3(16384 / 128, 1024 / 128), 256, 0, stream>>>(
      xb, wT, biasf, h, 1024, 16384, 4096);

  // W_out (16384 x 2048) -> transpose -> W2T (2048 x 16384) bf16 (reuse region)
  transpose_cvt_kernel<false><<<dim3(16384 / 64, 2048 / 64), 256, 0, stream>>>(
      W_out, wT, 16384, 2048, nullptr);

  // out = h @ W2T^T + b_out  (1024 x 2048, f32 out)
  gemm_kernel<2, 4, false><<<dim3(2048 / 128, 1024 / 64), 256, 0, stream>>>(
      h, wT, b_out, out, 1024, 2048, 16384);
}

// Round 2
// 416.649 us; speedup vs baseline: 1.3667x; 1.3667x over previous
//
#include <hip/hip_runtime.h>
#include <stdint.h>

#define AS1 __attribute__((address_space(1)))
#define AS3 __attribute__((address_space(3)))

typedef float v4f __attribute__((ext_vector_type(4)));
typedef __bf16 v8bf __attribute__((ext_vector_type(8)));

static_assert(sizeof(v8bf) == 16, "v8bf must be 16B");

__device__ __forceinline__ unsigned short f2bf(float f) {
  unsigned int x = __float_as_uint(f);
  x += 0x7fffu + ((x >> 16) & 1u);
  return (unsigned short)(x >> 16);
}

__device__ __forceinline__ void async16(void* lds, const void* g) {
  __builtin_amdgcn_global_load_lds((const AS1 unsigned int*)g,
                                   (AS3 unsigned int*)lds, 16, 0, 0);
}

// ---------------- prep kernels ----------------

// M = 0.99*I - 0.001*(W_e + W_e^T); m3 = M^3  (64 floats)
__global__ void prep_m3_kernel(const float* __restrict__ We, float* __restrict__ m3) {
  __shared__ float Ms[64], M2[64];
  int t = threadIdx.x;        // 64 threads
  int i = t >> 3, j = t & 7;
  float wsym = We[i * 8 + j] + We[j * 8 + i];
  Ms[t] = (i == j ? 0.99f : 0.0f) - 0.001f * wsym;
  __syncthreads();
  float s = 0.f;
#pragma unroll
  for (int p = 0; p < 8; ++p) s += Ms[i * 8 + p] * Ms[p * 8 + j];
  M2[t] = s;
  __syncthreads();
  s = 0.f;
#pragma unroll
  for (int p = 0; p < 8; ++p) s += M2[i * 8 + p] * Ms[p * 8 + j];
  m3[t] = s;
}

// b_in'[n] = sum_p b_in[(n&~7)+p] * m3[p][n&7]   (16384 outputs)
__global__ void fold_bias_kernel(const float* __restrict__ b, const float* __restrict__ m3,
                                 float* __restrict__ bo) {
  int n = blockIdx.x * 256 + threadIdx.x;
  int j = n & 7, lo = n & ~7;
  float s = 0.f;
#pragma unroll
  for (int p = 0; p < 8; ++p) s += b[lo + p] * m3[p * 8 + j];
  bo[n] = s;
}

// f32 -> bf16 elementwise, 8 elems/thread
__global__ void cvt_bf16_kernel(const float* __restrict__ in, unsigned short* __restrict__ out) {
  int i = (blockIdx.x * 256 + threadIdx.x) * 8;
  float4 a = *(const float4*)(in + i);
  float4 b = *(const float4*)(in + i + 4);
  alignas(16) unsigned short r[8] = {f2bf(a.x), f2bf(a.y), f2bf(a.z), f2bf(a.w),
                                     f2bf(b.x), f2bf(b.y), f2bf(b.z), f2bf(b.w)};
  *(uint4*)(out + i) = *(const uint4*)r;
}

// Transpose (K x N f32, row-major) -> (N x K bf16, row-major), optionally folding
// M3 along n within 8-column groups: out[n][k] = sum_p in[k][(n&~7)+p]*m3[p][n&7]
template <bool FOLD>
__global__ __launch_bounds__(256) void transpose_cvt_kernel(
    const float* __restrict__ in, unsigned short* __restrict__ outT,
    int K, int N, const float* __restrict__ m3) {
  __shared__ float tile[64][65];
  __shared__ float m3s[64];
  const int t = threadIdx.x;
  const int k0 = blockIdx.x * 64, n0 = blockIdx.y * 64;
  if (FOLD && t < 64) m3s[t] = m3[t];
  {
    int row = t >> 2, ch = t & 3;
    const float* g = in + (size_t)(k0 + row) * N + n0 + ch * 16;
    float4 v0 = ((const float4*)g)[0];
    float4 v1 = ((const float4*)g)[1];
    float4 v2 = ((const float4*)g)[2];
    float4 v3 = ((const float4*)g)[3];
    float* d = &tile[row][ch * 16];
    d[0] = v0.x; d[1] = v0.y; d[2] = v0.z; d[3] = v0.w;
    d[4] = v1.x; d[5] = v1.y; d[6] = v1.z; d[7] = v1.w;
    d[8] = v2.x; d[9] = v2.y; d[10] = v2.z; d[11] = v2.w;
    d[12] = v3.x; d[13] = v3.y; d[14] = v3.z; d[15] = v3.w;
  }
  __syncthreads();
  const int nl = t >> 2, kch = t & 3;
  alignas(16) unsigned short r[16];
  if (FOLD) {
    const int j = nl & 7, lo = nl & 56;
    float mcol[8];
#pragma unroll
    for (int p = 0; p < 8; ++p) mcol[p] = m3s[p * 8 + j];
#pragma unroll
    for (int i = 0; i < 16; ++i) {
      int kk = kch * 16 + i;
      float s = 0.f;
#pragma unroll
      for (int p = 0; p < 8; ++p) s += tile[kk][lo + p] * mcol[p];
      r[i] = f2bf(s);
    }
  } else {
#pragma unroll
    for (int i = 0; i < 16; ++i) r[i] = f2bf(tile[kch * 16 + i][nl]);
  }
  uint4* dst = (uint4*)(outT + (size_t)(n0 + nl) * K + k0 + kch * 16);
  dst[0] = ((const uint4*)r)[0];
  dst[1] = ((const uint4*)r)[1];
}

// ---------------- GEMM (m97-style 128-tile, bf16 MFMA 16x16x32) ----------------
// C[M][N] = A[M][K]@BT[N][K]^T (+bias). ldk = row stride of A and BT (elements).
// SPLITK: blockIdx.z picks K-chunk [z*K, z*K+K); writes f32 partial at
// Cout + z*M*N, no bias.
// Block: 256 threads = 4 waves in 2x2; wave tile = (MF*16) x (NF*16).
template <int MF, int NF, bool OUT_BF16, bool SPLITK>
__global__ __launch_bounds__(256, 2) void gemm_kernel(
    const unsigned short* __restrict__ A, const unsigned short* __restrict__ BT,
    const float* __restrict__ bias, void* __restrict__ Cout,
    int M, int N, int K, int ldk) {
  constexpr int BM = 32 * MF, BN = 32 * NF;
  constexpr int ISS = (BM + BN) / 64;  // 4KB staging issues per K-step
  __shared__ unsigned short lds[(BM + BN) * 32];

  const int t = threadIdx.x;
  const int bn = blockIdx.x, bm = blockIdx.y;
  const int m0 = bm * BM, n0 = bn * BN;
  const int kb = SPLITK ? blockIdx.z * K : 0;
  const int lane = t & 63;
  const int w = t >> 6;
  const int wr = w >> 1, wc = w & 1;
  const int r16 = lane & 15, kc = lane >> 4;

  v4f acc[MF][NF];
#pragma unroll
  for (int m = 0; m < MF; ++m)
#pragma unroll
    for (int n = 0; n < NF; ++n) acc[m][n] = (v4f){0.f, 0.f, 0.f, 0.f};

  for (int k0 = kb; k0 < kb + K; k0 += 32) {
#pragma unroll
    for (int i = 0; i < ISS; ++i) {
      int slot = i * 256 + t;          // 16-byte slot index
      int row = slot >> 2, ch = slot & 3;
      const unsigned short* g =
          (row < BM) ? (A + (size_t)(m0 + row) * ldk + k0 + ch * 8)
                     : (BT + (size_t)(n0 + row - BM) * ldk + k0 + ch * 8);
      async16(&lds[slot * 8], g);
    }
    __syncthreads();   // compiler drains vmcnt before s_barrier

    v8bf af[MF], bfr[NF];
#pragma unroll
    for (int m = 0; m < MF; ++m)
      af[m] = *(const v8bf*)&lds[(wr * MF * 16 + m * 16 + r16) * 32 + kc * 8];
#pragma unroll
    for (int n = 0; n < NF; ++n)
      bfr[n] = *(const v8bf*)&lds[(BM + wc * NF * 16 + n * 16 + r16) * 32 + kc * 8];
#pragma unroll
    for (int m = 0; m < MF; ++m)
#pragma unroll
      for (int n = 0; n < NF; ++n)
        acc[m][n] = __builtin_amdgcn_mfma_f32_16x16x32_bf16(af[m], bfr[n], acc[m][n], 0, 0, 0);
    __syncthreads();   // protect LDS from next iteration's staging
  }

  float* Cp = (float*)Cout + (SPLITK ? (size_t)blockIdx.z * M * N : 0);
#pragma unroll
  for (int m = 0; m < MF; ++m) {
    int grow = m0 + wr * MF * 16 + m * 16 + kc * 4;
#pragma unroll
    for (int n = 0; n < NF; ++n) {
      int gcol = n0 + wc * NF * 16 + n * 16 + r16;
      float bv = SPLITK ? 0.f : bias[gcol];
#pragma unroll
      for (int j = 0; j < 4; ++j) {
        float v = acc[m][n][j] + bv;
        size_t idx = (size_t)(grow + j) * N + gcol;
        if (OUT_BF16)
          ((unsigned short*)Cout)[idx] = f2bf(v);
        else
          Cp[idx] = v;
      }
    }
  }
}

// out[i] = sum_s part[s*MN + i] + bias[i % N], 4 elems/thread, fixed order
__global__ void reduce_splitk_kernel(const float* __restrict__ part,
                                     const float* __restrict__ bias,
                                     float* __restrict__ out, int MN, int N, int S) {
  int i = (blockIdx.x * 256 + threadIdx.x) * 4;
  float4 s = *(const float4*)(part + i);
  for (int k = 1; k < S; ++k) {
    float4 v = *(const float4*)(part + (size_t)k * MN + i);
    s.x += v.x; s.y += v.y; s.z += v.z; s.w += v.w;
  }
  int n = i & (N - 1);
  const float4 bv = *(const float4*)(bias + n);
  s.x += bv.x; s.y += bv.y; s.z += bv.z; s.w += bv.w;
  *(float4*)(out + i) = s;
}

// ---------------- launch ----------------

extern "C" void kernel_launch(void* const* d_in, const int* in_sizes, int n_in,
                              void* d_out, int out_size, void* d_ws, size_t ws_size,
                              hipStream_t stream) {
  const float* x     = (const float*)d_in[0];   // 1024 x 4096
  const float* W_in  = (const float*)d_in[1];   // 4096 x 16384
  const float* b_in  = (const float*)d_in[2];   // 16384
  const float* W_e   = (const float*)d_in[3];   // 8 x 8
  const float* W_out = (const float*)d_in[4];   // 16384 x 2048
  const float* b_out = (const float*)d_in[5];   // 2048
  float* out = (float*)d_out;                   // 1024 x 2048 f32

  char* ws = (char*)d_ws;
  const size_t OFF_M3   = 0;                    // 256 B
  const size_t OFF_BIAS = 4096;                 // 64 KB
  const size_t OFF_X    = 1ull << 20;           // 8 MB   (x bf16)
  const size_t OFF_H    = 10ull << 20;          // 32 MB  (h bf16)
  const size_t OFF_W    = 48ull << 20;          // W1T 128MB (48..176); later W2T 64MB (48..112)
  const size_t OFF_P    = 112ull << 20;         // split-K partials 64MB (112..176)
  float* m3            = (float*)(ws + OFF_M3);
  float* biasf         = (float*)(ws + OFF_BIAS);
  unsigned short* xb   = (unsigned short*)(ws + OFF_X);
  unsigned short* h    = (unsigned short*)(ws + OFF_H);
  unsigned short* wT   = (unsigned short*)(ws + OFF_W);
  float* part          = (float*)(ws + OFF_P);

  prep_m3_kernel<<<1, 64, 0, stream>>>(W_e, m3);
  fold_bias_kernel<<<64, 256, 0, stream>>>(b_in, m3, biasf);
  cvt_bf16_kernel<<<2048, 256, 0, stream>>>(x, xb);  // 1024*4096 / (256*8)

  // W_in (4096 x 16384) -> fold M3 + transpose -> W1T (16384 x 4096) bf16
  transpose_cvt_kernel<true><<<dim3(4096 / 64, 16384 / 64), 256, 0, stream>>>(
      W_in, wT, 4096, 16384, m3);

  // h = x @ W1T^T + b_in'   (1024 x 16384, bf16 out)
  gemm_kernel<4, 4, true, false><<<dim3(16384 / 128, 1024 / 128), 256, 0, stream>>>(
      xb, wT, biasf, h, 1024, 16384, 4096, 4096);

  // W_out (16384 x 2048) -> transpose -> W2T (2048 x 16384) bf16 (reuse region)
  transpose_cvt_kernel<false><<<dim3(16384 / 64, 2048 / 64), 256, 0, stream>>>(
      W_out, wT, 16384, 2048, nullptr);

  // partials[z] = h @ W2T^T over K-chunk z  (split-K 8 x 2048)
  gemm_kernel<4, 4, false, true><<<dim3(2048 / 128, 1024 / 128, 8), 256, 0, stream>>>(
      h, wT, nullptr, part, 1024, 2048, 2048, 16384);

  // out = sum_z partials[z] + b_out
  reduce_splitk_kernel<<<2048, 256, 0, stream>>>(part, b_out, out, 1024 * 2048, 2048, 8);
}

// Round 3
// 363.788 us; speedup vs baseline: 1.5653x; 1.1453x over previous
//
#include <hip/hip_runtime.h>
#include <stdint.h>

#define AS1 __attribute__((address_space(1)))
#define AS3 __attribute__((address_space(3)))

typedef float v4f __attribute__((ext_vector_type(4)));
typedef __bf16 v8bf __attribute__((ext_vector_type(8)));

static_assert(sizeof(v8bf) == 16, "v8bf must be 16B");

__device__ __forceinline__ unsigned short f2bf(float f) {
  unsigned int x = __float_as_uint(f);
  x += 0x7fffu + ((x >> 16) & 1u);
  return (unsigned short)(x >> 16);
}

__device__ __forceinline__ void async16(void* lds, const void* g) {
  __builtin_amdgcn_global_load_lds((const AS1 unsigned int*)g,
                                   (AS3 unsigned int*)lds, 16, 0, 0);
}

// ---------------- prep kernels ----------------

// M = 0.99*I - 0.001*(W_e + W_e^T); m3 = M^3  (64 floats)
__global__ void prep_m3_kernel(const float* __restrict__ We, float* __restrict__ m3) {
  __shared__ float Ms[64], M2[64];
  int t = threadIdx.x;        // 64 threads
  int i = t >> 3, j = t & 7;
  float wsym = We[i * 8 + j] + We[j * 8 + i];
  Ms[t] = (i == j ? 0.99f : 0.0f) - 0.001f * wsym;
  __syncthreads();
  float s = 0.f;
#pragma unroll
  for (int p = 0; p < 8; ++p) s += Ms[i * 8 + p] * Ms[p * 8 + j];
  M2[t] = s;
  __syncthreads();
  s = 0.f;
#pragma unroll
  for (int p = 0; p < 8; ++p) s += M2[i * 8 + p] * Ms[p * 8 + j];
  m3[t] = s;
}

// b_in'[n] = sum_p b_in[(n&~7)+p] * m3[p][n&7]   (16384 outputs)
__global__ void fold_bias_kernel(const float* __restrict__ b, const float* __restrict__ m3,
                                 float* __restrict__ bo) {
  int n = blockIdx.x * 256 + threadIdx.x;
  int j = n & 7, lo = n & ~7;
  float s = 0.f;
#pragma unroll
  for (int p = 0; p < 8; ++p) s += b[lo + p] * m3[p * 8 + j];
  bo[n] = s;
}

// f32 -> bf16 elementwise, 8 elems/thread
__global__ void cvt_bf16_kernel(const float* __restrict__ in, unsigned short* __restrict__ out) {
  int i = (blockIdx.x * 256 + threadIdx.x) * 8;
  float4 a = *(const float4*)(in + i);
  float4 b = *(const float4*)(in + i + 4);
  alignas(16) unsigned short r[8] = {f2bf(a.x), f2bf(a.y), f2bf(a.z), f2bf(a.w),
                                     f2bf(b.x), f2bf(b.y), f2bf(b.z), f2bf(b.w)};
  *(uint4*)(out + i) = *(const uint4*)r;
}

// Transpose (K x N f32, row-major) -> (N x K bf16, row-major), optionally folding
// M3 along n within 8-column groups: out[n][k] = sum_p in[k][(n&~7)+p]*m3[p][n&7]
template <bool FOLD>
__global__ __launch_bounds__(256) void transpose_cvt_kernel(
    const float* __restrict__ in, unsigned short* __restrict__ outT,
    int K, int N, const float* __restrict__ m3) {
  __shared__ float tile[64][65];
  __shared__ float m3s[64];
  const int t = threadIdx.x;
  const int k0 = blockIdx.x * 64, n0 = blockIdx.y * 64;
  if (FOLD && t < 64) m3s[t] = m3[t];
  {
    int row = t >> 2, ch = t & 3;
    const float* g = in + (size_t)(k0 + row) * N + n0 + ch * 16;
    float4 v0 = ((const float4*)g)[0];
    float4 v1 = ((const float4*)g)[1];
    float4 v2 = ((const float4*)g)[2];
    float4 v3 = ((const float4*)g)[3];
    float* d = &tile[row][ch * 16];
    d[0] = v0.x; d[1] = v0.y; d[2] = v0.z; d[3] = v0.w;
    d[4] = v1.x; d[5] = v1.y; d[6] = v1.z; d[7] = v1.w;
    d[8] = v2.x; d[9] = v2.y; d[10] = v2.z; d[11] = v2.w;
    d[12] = v3.x; d[13] = v3.y; d[14] = v3.z; d[15] = v3.w;
  }
  __syncthreads();
  const int nl = t >> 2, kch = t & 3;
  alignas(16) unsigned short r[16];
  if (FOLD) {
    const int j = nl & 7, lo = nl & 56;
    float mcol[8];
#pragma unroll
    for (int p = 0; p < 8; ++p) mcol[p] = m3s[p * 8 + j];
#pragma unroll
    for (int i = 0; i < 16; ++i) {
      int kk = kch * 16 + i;
      float s = 0.f;
#pragma unroll
      for (int p = 0; p < 8; ++p) s += tile[kk][lo + p] * mcol[p];
      r[i] = f2bf(s);
    }
  } else {
#pragma unroll
    for (int i = 0; i < 16; ++i) r[i] = f2bf(tile[kch * 16 + i][nl]);
  }
  uint4* dst = (uint4*)(outT + (size_t)(n0 + nl) * K + k0 + kch * 16);
  dst[0] = ((const uint4*)r)[0];
  dst[1] = ((const uint4*)r)[1];
}

// ---------------- 256x256 phase-split GEMM (bf16 MFMA 16x16x32) ----------------
// C[M][N] = A[M][K]@BT[N][K]^T (+bias). ldk = row stride of A and BT (elements).
// 512 threads = 8 waves (2 M-rows x 4 N-cols); wave tile 128x64; BK=64.
// LDS 128KB: 2 buffers x (A[256][64] | B[256][64]) bf16, XOR-swizzled
// (element (r,k) at byte r*128 + ((k/8 ^ (r&7))<<4)); staging is linear
// global_load_lds with pre-swizzled per-lane global source (rule #21).
// Per K-tile: 4 phases (quadrants), barrier/lgkmcnt/setprio per template;
// all 8 stage loads for tile t+1 issue in phases 0-1 (cover ~= full tile,
// ~2000cy >> HBM latency), single vmcnt(0) drain at tile boundary.
template <bool OUT_BF16, bool SPLITK>
__global__ __launch_bounds__(512, 2) void gemm256_kernel(
    const unsigned short* __restrict__ A, const unsigned short* __restrict__ BT,
    const float* __restrict__ bias, void* __restrict__ Cout,
    int M, int N, int K, int ldk) {
  __shared__ char ldsc[131072];

  // bijective XCD swizzle (nwg % 8 == 0 by construction)
  const int nx = gridDim.x, ny = gridDim.y;
  const int flat = blockIdx.x + nx * (blockIdx.y + ny * blockIdx.z);
  const int cpx = (nx * ny * gridDim.z) >> 3;
  const int swz = (flat & 7) * cpx + (flat >> 3);
  const int bn = swz % nx;
  const int rest = swz / nx;
  const int bm = rest % ny;
  const int bz = rest / ny;
  const int m0 = bm * 256, n0 = bn * 256;
  const int kb = SPLITK ? bz * K : 0;

  const int t = threadIdx.x;
  const int lane = t & 63, w = t >> 6;
  const int wr = w >> 2, wn = w & 3;
  const int r16 = lane & 15, kc = lane >> 4;
  const int xorv = (r16 & 7) << 4;
  const int acol0 = (kc << 4) ^ xorv;            // kk=0 byte col
  const int acol1 = ((4 | kc) << 4) ^ xorv;      // kk=1 byte col
  const int abase = wr * 16384 + r16 * 128;      // A region row base
  const int bbase = 32768 + wn * 8192 + r16 * 128;  // B region row base

  // staging: issue i covers LDS rows [i*64 + w*8 + lane/8]; source k-chunk
  // pre-swizzled so linear LDS write == swizzled storage.
  const int srow = w * 8 + (lane >> 3);
  const int scol = ((lane & 7) ^ (lane >> 3)) * 8;
  const int sdst = w * 1024 + lane * 16;         // + i*8192 per issue
  const unsigned short* gAp = A + (size_t)(m0 + srow) * ldk + kb + scol;
  const unsigned short* gBp = BT + (size_t)(n0 + srow) * ldk + kb + scol;

  v4f acc[8][4];
#pragma unroll
  for (int mi = 0; mi < 8; ++mi)
#pragma unroll
    for (int nj = 0; nj < 4; ++nj) acc[mi][nj] = (v4f){0.f, 0.f, 0.f, 0.f};

#define STAGE_A(OB)                                                        \
  _Pragma("unroll") for (int i = 0; i < 4; ++i)                            \
      async16(ldsc + (OB) + i * 8192 + sdst, gAp + (size_t)(i * 64) * ldk);
#define STAGE_B(OB)                                                        \
  _Pragma("unroll") for (int i = 0; i < 4; ++i)                            \
      async16(ldsc + (OB) + 32768 + i * 8192 + sdst, gBp + (size_t)(i * 64) * ldk);
#define LOAD_A(BB, MH)                                                     \
  _Pragma("unroll") for (int m = 0; m < 4; ++m) {                          \
    a[m * 2 + 0] = *(const v8bf*)(ldsc + (BB) + abase + (MH) * 8192 + m * 2048 + acol0); \
    a[m * 2 + 1] = *(const v8bf*)(ldsc + (BB) + abase + (MH) * 8192 + m * 2048 + acol1); \
  }
#define LOAD_B(BB, NH, BR)                                                 \
  _Pragma("unroll") for (int n = 0; n < 2; ++n) {                          \
    BR[n * 2 + 0] = *(const v8bf*)(ldsc + (BB) + bbase + (NH) * 4096 + n * 2048 + acol0); \
    BR[n * 2 + 1] = *(const v8bf*)(ldsc + (BB) + bbase + (NH) * 4096 + n * 2048 + acol1); \
  }
#define MFMA_QUAD(MH, NH, BR)                                              \
  _Pragma("unroll") for (int m = 0; m < 4; ++m) {                          \
    _Pragma("unroll") for (int n = 0; n < 2; ++n) {                        \
      acc[(MH) * 4 + m][(NH) * 2 + n] = __builtin_amdgcn_mfma_f32_16x16x32_bf16( \
          a[m * 2 + 0], BR[n * 2 + 0], acc[(MH) * 4 + m][(NH) * 2 + n], 0, 0, 0); \
      acc[(MH) * 4 + m][(NH) * 2 + n] = __builtin_amdgcn_mfma_f32_16x16x32_bf16( \
          a[m * 2 + 1], BR[n * 2 + 1], acc[(MH) * 4 + m][(NH) * 2 + n], 0, 0, 0); \
    }                                                                      \
  }
#define PHASE_SYNC()                                          \
  __builtin_amdgcn_s_barrier();                               \
  asm volatile("s_waitcnt lgkmcnt(0)" ::: "memory");          \
  __builtin_amdgcn_sched_barrier(0);                          \
  __builtin_amdgcn_s_setprio(1);
#define PHASE_END()                                           \
  __builtin_amdgcn_s_setprio(0);                              \
  __builtin_amdgcn_s_barrier();

  // prologue: stage tile 0 into buffer 0
  STAGE_A(0);
  STAGE_B(0);
  gAp += 64;
  gBp += 64;

  const int NT = K >> 6;
  int buf = 0;
  for (int tt = 0; tt < NT; ++tt) {
    // tile boundary: own stages drained, then all waves' stages visible
    asm volatile("s_waitcnt vmcnt(0)" ::: "memory");
    __builtin_amdgcn_sched_barrier(0);
    __builtin_amdgcn_s_barrier();

    const int bb = buf << 16;
    const int ob = (buf ^ 1) << 16;
    const bool pf = (tt + 1 < NT);
    v8bf a[8], b0[4], b1[4];

    // P0: quadrant (0,0); stage next A
    LOAD_A(bb, 0);
    LOAD_B(bb, 0, b0);
    if (pf) { STAGE_A(ob); }
    PHASE_SYNC();
    MFMA_QUAD(0, 0, b0);
    PHASE_END();

    // P1: quadrant (0,1); stage next B
    LOAD_B(bb, 1, b1);
    if (pf) { STAGE_B(ob); gAp += 64; gBp += 64; }
    PHASE_SYNC();
    MFMA_QUAD(0, 1, b1);
    PHASE_END();

    // P2: quadrant (1,1)
    LOAD_A(bb, 1);
    PHASE_SYNC();
    MFMA_QUAD(1, 1, b1);
    PHASE_END();

    // P3: quadrant (1,0)
    LOAD_B(bb, 0, b0);
    PHASE_SYNC();
    MFMA_QUAD(1, 0, b0);
    PHASE_END();

    buf ^= 1;
  }

  float* Cp = (float*)Cout + (SPLITK ? (size_t)bz * M * N : 0);
#pragma unroll
  for (int mi = 0; mi < 8; ++mi) {
    int grow = m0 + wr * 128 + mi * 16 + kc * 4;
#pragma unroll
    for (int nj = 0; nj < 4; ++nj) {
      int gcol = n0 + wn * 64 + nj * 16 + r16;
      float bv = SPLITK ? 0.f : bias[gcol];
#pragma unroll
      for (int j = 0; j < 4; ++j) {
        float v = acc[mi][nj][j] + bv;
        size_t idx = (size_t)(grow + j) * N + gcol;
        if (OUT_BF16)
          ((unsigned short*)Cout)[idx] = f2bf(v);
        else
          Cp[idx] = v;
      }
    }
  }
#undef STAGE_A
#undef STAGE_B
#undef LOAD_A
#undef LOAD_B
#undef MFMA_QUAD
#undef PHASE_SYNC
#undef PHASE_END
}

// out[i] = sum_s part[s*MN + i] + bias[i % N], 4 elems/thread, fixed order
__global__ void reduce_splitk_kernel(const float* __restrict__ part,
                                     const float* __restrict__ bias,
                                     float* __restrict__ out, int MN, int N, int S) {
  int i = (blockIdx.x * 256 + threadIdx.x) * 4;
  float4 s = *(const float4*)(part + i);
  for (int k = 1; k < S; ++k) {
    float4 v = *(const float4*)(part + (size_t)k * MN + i);
    s.x += v.x; s.y += v.y; s.z += v.z; s.w += v.w;
  }
  int n = i & (N - 1);
  const float4 bv = *(const float4*)(bias + n);
  s.x += bv.x; s.y += bv.y; s.z += bv.z; s.w += bv.w;
  *(float4*)(out + i) = s;
}

// ---------------- launch ----------------

extern "C" void kernel_launch(void* const* d_in, const int* in_sizes, int n_in,
                              void* d_out, int out_size, void* d_ws, size_t ws_size,
                              hipStream_t stream) {
  const float* x     = (const float*)d_in[0];   // 1024 x 4096
  const float* W_in  = (const float*)d_in[1];   // 4096 x 16384
  const float* b_in  = (const float*)d_in[2];   // 16384
  const float* W_e   = (const float*)d_in[3];   // 8 x 8
  const float* W_out = (const float*)d_in[4];   // 16384 x 2048
  const float* b_out = (const float*)d_in[5];   // 2048
  float* out = (float*)d_out;                   // 1024 x 2048 f32

  char* ws = (char*)d_ws;
  const size_t OFF_M3   = 0;                    // 256 B
  const size_t OFF_BIAS = 4096;                 // 64 KB
  const size_t OFF_X    = 1ull << 20;           // 8 MB   (x bf16)
  const size_t OFF_H    = 10ull << 20;          // 32 MB  (h bf16)
  const size_t OFF_W    = 48ull << 20;          // W1T 128MB (48..176); later W2T 64MB (48..112)
  const size_t OFF_P    = 112ull << 20;         // split-K partials 64MB (112..176)
  float* m3            = (float*)(ws + OFF_M3);
  float* biasf         = (float*)(ws + OFF_BIAS);
  unsigned short* xb   = (unsigned short*)(ws + OFF_X);
  unsigned short* h    = (unsigned short*)(ws + OFF_H);
  unsigned short* wT   = (unsigned short*)(ws + OFF_W);
  float* part          = (float*)(ws + OFF_P);

  prep_m3_kernel<<<1, 64, 0, stream>>>(W_e, m3);
  fold_bias_kernel<<<64, 256, 0, stream>>>(b_in, m3, biasf);
  cvt_bf16_kernel<<<2048, 256, 0, stream>>>(x, xb);  // 1024*4096 / (256*8)

  // W_in (4096 x 16384) -> fold M3 + transpose -> W1T (16384 x 4096) bf16
  transpose_cvt_kernel<true><<<dim3(4096 / 64, 16384 / 64), 256, 0, stream>>>(
      W_in, wT, 4096, 16384, m3);

  // h = x @ W1T^T + b_in'   (1024 x 16384, bf16 out)
  gemm256_kernel<true, false><<<dim3(16384 / 256, 1024 / 256), 512, 0, stream>>>(
      xb, wT, biasf, h, 1024, 16384, 4096, 4096);

  // W_out (16384 x 2048) -> transpose -> W2T (2048 x 16384) bf16 (reuse region)
  transpose_cvt_kernel<false><<<dim3(16384 / 64, 2048 / 64), 256, 0, stream>>>(
      W_out, wT, 16384, 2048, nullptr);

  // partials[z] = h @ W2T^T over K-chunk z  (split-K 8 x 2048)
  gemm256_kernel<false, true><<<dim3(2048 / 256, 1024 / 256, 8), 512, 0, stream>>>(
      h, wT, nullptr, part, 1024, 2048, 2048, 16384);

  // out = sum_z partials[z] + b_out
  reduce_splitk_kernel<<<2048, 256, 0, stream>>>(part, b_out, out, 1024 * 2048, 2048, 8);
}

// Round 4
// 319.488 us; speedup vs baseline: 1.7824x; 1.1387x over previous
//
#include <hip/hip_runtime.h>
#include <stdint.h>

#define AS1 __attribute__((address_space(1)))
#define AS3 __attribute__((address_space(3)))

typedef float v4f __attribute__((ext_vector_type(4)));
typedef __bf16 v8bf __attribute__((ext_vector_type(8)));
typedef __bf16 bf16x4 __attribute__((ext_vector_type(4)));

static_assert(sizeof(v8bf) == 16, "v8bf must be 16B");
static_assert(sizeof(bf16x4) == 8, "bf16x4 must be 8B");

__device__ __forceinline__ unsigned short f2bf(float f) {
  unsigned int x = __float_as_uint(f);
  x += 0x7fffu + ((x >> 16) & 1u);
  return (unsigned short)(x >> 16);
}

__device__ __forceinline__ void async16(void* lds, const void* g) {
  __builtin_amdgcn_global_load_lds((const AS1 unsigned int*)g,
                                   (AS3 unsigned int*)lds, 16, 0, 0);
}

// ---------------- prep kernels ----------------

// M = 0.99*I - 0.001*(W_e + W_e^T); m3 = M^3  (64 floats)
__global__ void prep_m3_kernel(const float* __restrict__ We, float* __restrict__ m3) {
  __shared__ float Ms[64], M2[64];
  int t = threadIdx.x;        // 64 threads
  int i = t >> 3, j = t & 7;
  float wsym = We[i * 8 + j] + We[j * 8 + i];
  Ms[t] = (i == j ? 0.99f : 0.0f) - 0.001f * wsym;
  __syncthreads();
  float s = 0.f;
#pragma unroll
  for (int p = 0; p < 8; ++p) s += Ms[i * 8 + p] * Ms[p * 8 + j];
  M2[t] = s;
  __syncthreads();
  s = 0.f;
#pragma unroll
  for (int p = 0; p < 8; ++p) s += M2[i * 8 + p] * Ms[p * 8 + j];
  m3[t] = s;
}

// f32 -> bf16 elementwise, 8 elems/thread
__global__ void cvt_bf16_kernel(const float* __restrict__ in, unsigned short* __restrict__ out) {
  int i = (blockIdx.x * 256 + threadIdx.x) * 8;
  float4 a = *(const float4*)(in + i);
  float4 b = *(const float4*)(in + i + 4);
  alignas(16) unsigned short r[8] = {f2bf(a.x), f2bf(a.y), f2bf(a.z), f2bf(a.w),
                                     f2bf(b.x), f2bf(b.y), f2bf(b.z), f2bf(b.w)};
  *(uint4*)(out + i) = *(const uint4*)r;
}

// In-place blade fold: h[g*8+j] = sum_p h_pre[g*8+p] * m3[p][j]
__global__ void fold_h_kernel(unsigned short* __restrict__ h, const float* __restrict__ m3) {
  __shared__ float m3s[64];
  int t = threadIdx.x;
  if (t < 64) m3s[t] = m3[t];
  __syncthreads();
  size_t g = ((size_t)blockIdx.x * 256 + t) * 8;
  uint4 raw = *(const uint4*)(h + g);
  const unsigned short* rp = (const unsigned short*)&raw;
  float v[8];
#pragma unroll
  for (int p = 0; p < 8; ++p) v[p] = __uint_as_float((unsigned int)rp[p] << 16);
  alignas(16) unsigned short o[8];
#pragma unroll
  for (int j = 0; j < 8; ++j) {
    float s = 0.f;
#pragma unroll
    for (int p = 0; p < 8; ++p) s += v[p] * m3s[p * 8 + j];
    o[j] = f2bf(s);
  }
  *(uint4*)(h + g) = *(const uint4*)o;
}

// ------- 256x256 phase-split GEMM, fused f32->bf16 transposed B-staging -------
// C[M][N] = A[M][K] @ Bsrc[K][N] (+bias). A is bf16 (k-contiguous, row stride
// ldkA); Bsrc is f32 row-major (row stride ldnB) — transposed+converted into
// LDS on the fly. SPLITK: blockIdx.z=K-chunk, writes f32 partial, no bias.
// 512 threads = 8 waves (2 M-rows x 4 N-cols); wave tile 128x64; BK=64.
// LDS 128KB: 2 x (A[256][64] | B[256][64]) bf16; layout: elem (r,k) at byte
// r*128 + (((k>>3) ^ (r&7))<<4) + (k&7)*2.  A staged linearly by
// global_load_lds with pre-swizzled global source; B staged via regs:
// 4x4 f32 block/thread/pass, in-register transpose+cvt, rotated-row b64
// writes (rot = (lane>>1)&3 spreads r&7 over 8 values -> ~2-way conflicts).
// Grid must be 256 blocks. XCD grouping (assumes XCD = flat%8):
//  !SPLITK: bn = xcd*8 + (idx&7), bm = idx>>3  (W-panel sharers co-XCD)
//   SPLITK: bz = xcd,  bn = idx&7, bm = idx>>3
template <bool OUT_BF16, bool SPLITK>
__global__ __launch_bounds__(512, 1) void gemm256f_kernel(
    const unsigned short* __restrict__ A, const float* __restrict__ Bsrc,
    const float* __restrict__ bias, void* __restrict__ Cout,
    int M, int N, int K, int ldkA, int ldnB) {
  __shared__ char ldsc[131072];

  const int flat = blockIdx.x + gridDim.x * (blockIdx.y + gridDim.y * blockIdx.z);
  const int xcd = flat & 7, idx = flat >> 3;   // 256 blocks total
  int bn, bm, bz;
  if (SPLITK) { bz = xcd; bn = idx & 7; bm = idx >> 3; }
  else        { bz = 0;   bn = xcd * 8 + (idx & 7); bm = idx >> 3; }
  const int m0 = bm * 256, n0 = bn * 256;
  const int kb = SPLITK ? bz * K : 0;

  const int t = threadIdx.x;
  const int lane = t & 63, w = t >> 6;
  const int wr = w >> 2, wn = w & 3;
  const int r16 = lane & 15, kc = lane >> 4;
  const int xorv = (r16 & 7) << 4;
  const int acol0 = (kc << 4) ^ xorv;               // kk=0 byte col
  const int acol1 = ((4 | kc) << 4) ^ xorv;         // kk=1 byte col
  const int abase = wr * 16384 + r16 * 128;         // A region row base
  const int bbase = 32768 + wn * 8192 + r16 * 128;  // B region row base

  // A staging (global_load_lds, pre-swizzled source)
  const int srow = w * 8 + (lane >> 3);
  const int scol = ((lane & 7) ^ (lane >> 3)) * 8;
  const int sdst = w * 1024 + lane * 16;            // + i*8192 per issue
  const unsigned short* gAp = A + (size_t)(m0 + srow) * ldkA + kb + scol;

  // B staging (reg): wave w stages k-rows w*4..+3 (pass0) and 32+w*4..+3
  // (pass1); lane covers n = 4*lane..+3.
  const int n0s = 4 * lane;
  const int rotc = (lane >> 1) & 3;
  const float* gB = Bsrc + (size_t)(kb + w * 4) * ldnB + n0 + n0s;

  v4f acc[8][4];
#pragma unroll
  for (int mi = 0; mi < 8; ++mi)
#pragma unroll
    for (int nj = 0; nj < 4; ++nj) acc[mi][nj] = (v4f){0.f, 0.f, 0.f, 0.f};

  float4 L[2][4];

#define STAGE_A(OB)                                                        \
  _Pragma("unroll") for (int i = 0; i < 4; ++i)                            \
      async16(ldsc + (OB) + i * 8192 + sdst, gAp + (size_t)(i * 64) * ldkA);
#define LOAD_BGLB()                                                        \
  _Pragma("unroll") for (int ii = 0; ii < 2; ++ii)                         \
      _Pragma("unroll") for (int j = 0; j < 4; ++j)                        \
          L[ii][j] = *(const float4*)(gB + (size_t)(ii * 32 + j) * ldnB);
#define CVT_WRITE_B(OB)                                                          \
  _Pragma("unroll") for (int ii = 0; ii < 2; ++ii) {                             \
    const int k4 = w * 4 + ii * 32;                                              \
    bf16x4 R0 = (bf16x4){(__bf16)L[ii][0].x, (__bf16)L[ii][1].x,                 \
                         (__bf16)L[ii][2].x, (__bf16)L[ii][3].x};                \
    bf16x4 R1 = (bf16x4){(__bf16)L[ii][0].y, (__bf16)L[ii][1].y,                 \
                         (__bf16)L[ii][2].y, (__bf16)L[ii][3].y};                \
    bf16x4 R2 = (bf16x4){(__bf16)L[ii][0].z, (__bf16)L[ii][1].z,                 \
                         (__bf16)L[ii][2].z, (__bf16)L[ii][3].z};                \
    bf16x4 R3 = (bf16x4){(__bf16)L[ii][0].w, (__bf16)L[ii][1].w,                 \
                         (__bf16)L[ii][2].w, (__bf16)L[ii][3].w};                \
    _Pragma("unroll") for (int d = 0; d < 4; ++d) {                              \
      int o = (d + rotc) & 3;                                                    \
      int row = n0s + o;                                                         \
      bf16x4 vv = (o & 2) ? ((o & 1) ? R3 : R2) : ((o & 1) ? R1 : R0);           \
      *(bf16x4*)(ldsc + (OB) + 32768 + row * 128 +                               \
                 ((((k4 >> 3) ^ (row & 7)) << 4) | ((k4 & 7) << 1))) = vv;       \
    }                                                                            \
  }
#define LOAD_A(BB, MH)                                                     \
  _Pragma("unroll") for (int m = 0; m < 4; ++m) {                          \
    a[m * 2 + 0] = *(const v8bf*)(ldsc + (BB) + abase + (MH) * 8192 + m * 2048 + acol0); \
    a[m * 2 + 1] = *(const v8bf*)(ldsc + (BB) + abase + (MH) * 8192 + m * 2048 + acol1); \
  }
#define LOAD_B(BB, NH, BR)                                                 \
  _Pragma("unroll") for (int n = 0; n < 2; ++n) {                          \
    BR[n * 2 + 0] = *(const v8bf*)(ldsc + (BB) + bbase + (NH) * 4096 + n * 2048 + acol0); \
    BR[n * 2 + 1] = *(const v8bf*)(ldsc + (BB) + bbase + (NH) * 4096 + n * 2048 + acol1); \
  }
#define MFMA_QUAD(MH, NH, BR)                                              \
  _Pragma("unroll") for (int m = 0; m < 4; ++m) {                          \
    _Pragma("unroll") for (int n = 0; n < 2; ++n) {                        \
      acc[(MH) * 4 + m][(NH) * 2 + n] = __builtin_amdgcn_mfma_f32_16x16x32_bf16( \
          a[m * 2 + 0], BR[n * 2 + 0], acc[(MH) * 4 + m][(NH) * 2 + n], 0, 0, 0); \
      acc[(MH) * 4 + m][(NH) * 2 + n] = __builtin_amdgcn_mfma_f32_16x16x32_bf16( \
          a[m * 2 + 1], BR[n * 2 + 1], acc[(MH) * 4 + m][(NH) * 2 + n], 0, 0, 0); \
    }                                                                      \
  }
#define PHASE_SYNC()                                          \
  __builtin_amdgcn_s_barrier();                               \
  asm volatile("s_waitcnt lgkmcnt(0)" ::: "memory");          \
  __builtin_amdgcn_sched_barrier(0);                          \
  __builtin_amdgcn_s_setprio(1);
#define PHASE_END()                                           \
  __builtin_amdgcn_s_setprio(0);                              \
  __builtin_amdgcn_s_barrier();

  // prologue: stage tile 0 into buffer 0
  LOAD_BGLB();
  STAGE_A(0);
  gAp += 64;
  CVT_WRITE_B(0);
  gB += (size_t)64 * ldnB;

  const int NT = K >> 6;
  int buf = 0;
  for (int tt = 0; tt < NT; ++tt) {
    // tile boundary: A-stages drained (vmcnt), B ds_writes drained (lgkm),
    // then barrier makes all waves' staging visible.
    asm volatile("s_waitcnt vmcnt(0) lgkmcnt(0)" ::: "memory");
    __builtin_amdgcn_sched_barrier(0);
    __builtin_amdgcn_s_barrier();

    const int bb = buf << 16;
    const int ob = (buf ^ 1) << 16;
    const bool pf = (tt + 1 < NT);
    v8bf a[8], b0[4], b1[4];

    // P0: quadrant (0,0); issue next-tile B gloads + A stage
    if (pf) { LOAD_BGLB(); STAGE_A(ob); gAp += 64; }
    LOAD_A(bb, 0);
    LOAD_B(bb, 0, b0);
    PHASE_SYNC();
    MFMA_QUAD(0, 0, b0);
    PHASE_END();

    // P1: quadrant (0,1)
    LOAD_B(bb, 1, b1);
    PHASE_SYNC();
    MFMA_QUAD(0, 1, b1);
    PHASE_END();

    // P2: quadrant (1,1); convert + write next-tile B into ob
    LOAD_A(bb, 1);
    if (pf) { CVT_WRITE_B(ob); gB += (size_t)64 * ldnB; }
    PHASE_SYNC();
    MFMA_QUAD(1, 1, b1);
    PHASE_END();

    // P3: quadrant (1,0)
    LOAD_B(bb, 0, b0);
    PHASE_SYNC();
    MFMA_QUAD(1, 0, b0);
    PHASE_END();

    buf ^= 1;
  }

  float* Cp = (float*)Cout + (SPLITK ? (size_t)bz * M * N : 0);
#pragma unroll
  for (int mi = 0; mi < 8; ++mi) {
    int grow = m0 + wr * 128 + mi * 16 + kc * 4;
#pragma unroll
    for (int nj = 0; nj < 4; ++nj) {
      int gcol = n0 + wn * 64 + nj * 16 + r16;
      float bv = SPLITK ? 0.f : bias[gcol];
#pragma unroll
      for (int j = 0; j < 4; ++j) {
        float v = acc[mi][nj][j] + bv;
        size_t idxo = (size_t)(grow + j) * N + gcol;
        if (OUT_BF16)
          ((unsigned short*)Cout)[idxo] = f2bf(v);
        else
          Cp[idxo] = v;
      }
    }
  }
#undef STAGE_A
#undef LOAD_BGLB
#undef CVT_WRITE_B
#undef LOAD_A
#undef LOAD_B
#undef MFMA_QUAD
#undef PHASE_SYNC
#undef PHASE_END
}

// out[i] = sum_s part[s*MN + i] + bias[i % N], 4 elems/thread, fixed order
__global__ void reduce_splitk_kernel(const float* __restrict__ part,
                                     const float* __restrict__ bias,
                                     float* __restrict__ out, int MN, int N, int S) {
  int i = (blockIdx.x * 256 + threadIdx.x) * 4;
  float4 s = *(const float4*)(part + i);
  for (int k = 1; k < S; ++k) {
    float4 v = *(const float4*)(part + (size_t)k * MN + i);
    s.x += v.x; s.y += v.y; s.z += v.z; s.w += v.w;
  }
  int n = i & (N - 1);
  const float4 bv = *(const float4*)(bias + n);
  s.x += bv.x; s.y += bv.y; s.z += bv.z; s.w += bv.w;
  *(float4*)(out + i) = s;
}

// ---------------- launch ----------------

extern "C" void kernel_launch(void* const* d_in, const int* in_sizes, int n_in,
                              void* d_out, int out_size, void* d_ws, size_t ws_size,
                              hipStream_t stream) {
  const float* x     = (const float*)d_in[0];   // 1024 x 4096
  const float* W_in  = (const float*)d_in[1];   // 4096 x 16384
  const float* b_in  = (const float*)d_in[2];   // 16384
  const float* W_e   = (const float*)d_in[3];   // 8 x 8
  const float* W_out = (const float*)d_in[4];   // 16384 x 2048
  const float* b_out = (const float*)d_in[5];   // 2048
  float* out = (float*)d_out;                   // 1024 x 2048 f32

  char* ws = (char*)d_ws;
  const size_t OFF_M3 = 0;                      // 256 B
  const size_t OFF_X  = 1ull << 20;             // 8 MB   (x bf16)
  const size_t OFF_H  = 10ull << 20;            // 32 MB  (h bf16)
  const size_t OFF_P  = 48ull << 20;            // 64 MB  split-K partials
  float* m3          = (float*)(ws + OFF_M3);
  unsigned short* xb = (unsigned short*)(ws + OFF_X);
  unsigned short* h  = (unsigned short*)(ws + OFF_H);
  float* part        = (float*)(ws + OFF_P);

  prep_m3_kernel<<<1, 64, 0, stream>>>(W_e, m3);
  cvt_bf16_kernel<<<2048, 256, 0, stream>>>(x, xb);  // 1024*4096 / (256*8)

  // h_pre = x @ W_in + b_in   (1024 x 16384, bf16 out; W staged f32->bf16 in-kernel)
  gemm256f_kernel<true, false><<<dim3(64, 4), 512, 0, stream>>>(
      xb, W_in, b_in, h, 1024, 16384, 4096, 4096, 16384);

  // h = h_pre * (I (x) M^3)  (in-place blade fold)
  fold_h_kernel<<<8192, 256, 0, stream>>>(h, m3);

  // partials[z] = h @ W_out over K-chunk z  (split-K 8 x 2048)
  gemm256f_kernel<false, true><<<dim3(8, 4, 8), 512, 0, stream>>>(
      h, W_out, nullptr, part, 1024, 2048, 2048, 16384, 2048);

  // out = sum_z partials[z] + b_out
  reduce_splitk_kernel<<<2048, 256, 0, stream>>>(part, b_out, out, 1024 * 2048, 2048, 8);
}

// Round 5
// 258.889 us; speedup vs baseline: 2.1996x; 1.2341x over previous
//
#include <hip/hip_runtime.h>
#include <stdint.h>

#define AS1 __attribute__((address_space(1)))
#define AS3 __attribute__((address_space(3)))

typedef float v4f __attribute__((ext_vector_type(4)));
typedef __bf16 v8bf __attribute__((ext_vector_type(8)));
typedef __bf16 bf16x4 __attribute__((ext_vector_type(4)));

static_assert(sizeof(v8bf) == 16, "v8bf must be 16B");
static_assert(sizeof(bf16x4) == 8, "bf16x4 must be 8B");

__device__ __forceinline__ unsigned short f2bf(float f) {
  unsigned int x = __float_as_uint(f);
  x += 0x7fffu + ((x >> 16) & 1u);
  return (unsigned short)(x >> 16);
}

__device__ __forceinline__ void async16(void* lds, const void* g) {
  __builtin_amdgcn_global_load_lds((const AS1 unsigned int*)g,
                                   (AS3 unsigned int*)lds, 16, 0, 0);
}

// ---------------- prep kernels ----------------

// M = 0.99*I - 0.001*(W_e + W_e^T); m3 = M^3  (64 floats)
__global__ void prep_m3_kernel(const float* __restrict__ We, float* __restrict__ m3) {
  __shared__ float Ms[64], M2[64];
  int t = threadIdx.x;        // 64 threads
  int i = t >> 3, j = t & 7;
  float wsym = We[i * 8 + j] + We[j * 8 + i];
  Ms[t] = (i == j ? 0.99f : 0.0f) - 0.001f * wsym;
  __syncthreads();
  float s = 0.f;
#pragma unroll
  for (int p = 0; p < 8; ++p) s += Ms[i * 8 + p] * Ms[p * 8 + j];
  M2[t] = s;
  __syncthreads();
  s = 0.f;
#pragma unroll
  for (int p = 0; p < 8; ++p) s += M2[i * 8 + p] * Ms[p * 8 + j];
  m3[t] = s;
}

// f32 -> bf16 elementwise, 8 elems/thread
__global__ void cvt_bf16_kernel(const float* __restrict__ in, unsigned short* __restrict__ out) {
  int i = (blockIdx.x * 256 + threadIdx.x) * 8;
  float4 a = *(const float4*)(in + i);
  float4 b = *(const float4*)(in + i + 4);
  alignas(16) unsigned short r[8] = {f2bf(a.x), f2bf(a.y), f2bf(a.z), f2bf(a.w),
                                     f2bf(b.x), f2bf(b.y), f2bf(b.z), f2bf(b.w)};
  *(uint4*)(out + i) = *(const uint4*)r;
}

// In-place blade fold: h[g*8+j] = sum_p h_pre[g*8+p] * m3[p][j]
__global__ void fold_h_kernel(unsigned short* __restrict__ h, const float* __restrict__ m3) {
  __shared__ float m3s[64];
  int t = threadIdx.x;
  if (t < 64) m3s[t] = m3[t];
  __syncthreads();
  size_t g = ((size_t)blockIdx.x * 256 + t) * 8;
  uint4 raw = *(const uint4*)(h + g);
  const unsigned short* rp = (const unsigned short*)&raw;
  float v[8];
#pragma unroll
  for (int p = 0; p < 8; ++p) v[p] = __uint_as_float((unsigned int)rp[p] << 16);
  alignas(16) unsigned short o[8];
#pragma unroll
  for (int j = 0; j < 8; ++j) {
    float s = 0.f;
#pragma unroll
    for (int p = 0; p < 8; ++p) s += v[p] * m3s[p * 8 + j];
    o[j] = f2bf(s);
  }
  *(uint4*)(h + g) = *(const uint4*)o;
}

// ------- 256x256 GEMM, fused f32->bf16 transposed B-staging, counted-wait -------
// C[M][N] = A[M][K] @ Bsrc[K][N] (+bias). A bf16 (k-contig, row stride ldkA);
// Bsrc f32 row-major (row stride ldnB), transposed+converted into LDS on the
// fly. SPLITK: blockIdx.z = K-chunk, f32 partial out, no bias.
// 512 threads = 8 waves (2 M x 4 N); wave tile 128x64; BK=64.
// LDS 128KB: 2 x (A[256][64] | B[256][64]) bf16; elem (r,k) at byte
// r*128 + (((k>>3) ^ (r&7))<<4) + (k&7)*2.
// Schedule (single region per tile, ONE barrier, counted waits — no phase
// boxes, no setprio; compiler interleaves ds_read/MFMA, 2 waves/SIMD slip):
//  tile t: CVT_WRITE_B(ob)   <- consumes L(t+1) loaded during tile t-1 (full-
//                               tile cover, vmcnt wait ~free)
//          STAGE_A(ob)       <- 4 gload_lds for A(t+1)
//          LOAD_BGLB         <- 8 f32x4 gloads for B(t+2) into L
//          sched_barrier; ds_reads(bb) + 64 MFMA; sched_barrier
//          s_waitcnt vmcnt(8) lgkmcnt(0)  <- drains A-stage (old), leaves the
//                               8 B-gloads in flight; never drains to 0
//          s_barrier
template <bool OUT_BF16, bool SPLITK>
__global__ __launch_bounds__(512, 1) void gemm256f_kernel(
    const unsigned short* __restrict__ A, const float* __restrict__ Bsrc,
    const float* __restrict__ bias, void* __restrict__ Cout,
    int M, int N, int K, int ldkA, int ldnB) {
  __shared__ char ldsc[131072];

  const int flat = blockIdx.x + gridDim.x * (blockIdx.y + gridDim.y * blockIdx.z);
  const int xcd = flat & 7, idx = flat >> 3;   // 256 blocks total
  int bn, bm, bz;
  if (SPLITK) { bz = xcd; bn = idx & 7; bm = idx >> 3; }
  else        { bz = 0;   bn = xcd * 8 + (idx & 7); bm = idx >> 3; }
  const int m0 = bm * 256, n0 = bn * 256;
  const int kb = SPLITK ? bz * K : 0;

  const int t = threadIdx.x;
  const int lane = t & 63, w = t >> 6;
  const int wr = w >> 2, wn = w & 3;
  const int r16 = lane & 15, kc = lane >> 4;
  const int xorv = (r16 & 7) << 4;
  const int acol0 = (kc << 4) ^ xorv;               // kk=0 byte col
  const int acol1 = ((4 | kc) << 4) ^ xorv;         // kk=1 byte col
  const int abase = wr * 16384 + r16 * 128;         // A region row base
  const int bbase = 32768 + wn * 8192 + r16 * 128;  // B region row base

  // A staging (global_load_lds, pre-swizzled source)
  const int srow = w * 8 + (lane >> 3);
  const int scol = ((lane & 7) ^ (lane >> 3)) * 8;
  const int sdst = w * 1024 + lane * 16;            // + i*8192 per issue
  const unsigned short* gAp = A + (size_t)(m0 + srow) * ldkA + kb + scol;

  // B staging (reg): wave w covers k-rows w*4..+3 (pass0), 32+w*4..+3 (pass1);
  // lane covers n = 4*lane..+3.
  const int n0s = 4 * lane;
  const int rotc = (lane >> 1) & 3;
  const float* gB = Bsrc + (size_t)(kb + w * 4) * ldnB + n0 + n0s;

  v4f acc[8][4];
#pragma unroll
  for (int mi = 0; mi < 8; ++mi)
#pragma unroll
    for (int nj = 0; nj < 4; ++nj) acc[mi][nj] = (v4f){0.f, 0.f, 0.f, 0.f};

  float4 L[2][4];

#define STAGE_A(OB)                                                        \
  _Pragma("unroll") for (int i = 0; i < 4; ++i)                            \
      async16(ldsc + (OB) + i * 8192 + sdst, gAp + (size_t)(i * 64) * ldkA);
#define LOAD_BGLB()                                                        \
  _Pragma("unroll") for (int ii = 0; ii < 2; ++ii)                         \
      _Pragma("unroll") for (int j = 0; j < 4; ++j)                        \
          L[ii][j] = *(const float4*)(gB + (size_t)(ii * 32 + j) * ldnB);
#define CVT_WRITE_B(OB)                                                          \
  _Pragma("unroll") for (int ii = 0; ii < 2; ++ii) {                             \
    const int k4 = w * 4 + ii * 32;                                              \
    bf16x4 R0 = (bf16x4){(__bf16)L[ii][0].x, (__bf16)L[ii][1].x,                 \
                         (__bf16)L[ii][2].x, (__bf16)L[ii][3].x};                \
    bf16x4 R1 = (bf16x4){(__bf16)L[ii][0].y, (__bf16)L[ii][1].y,                 \
                         (__bf16)L[ii][2].y, (__bf16)L[ii][3].y};                \
    bf16x4 R2 = (bf16x4){(__bf16)L[ii][0].z, (__bf16)L[ii][1].z,                 \
                         (__bf16)L[ii][2].z, (__bf16)L[ii][3].z};                \
    bf16x4 R3 = (bf16x4){(__bf16)L[ii][0].w, (__bf16)L[ii][1].w,                 \
                         (__bf16)L[ii][2].w, (__bf16)L[ii][3].w};                \
    _Pragma("unroll") for (int d = 0; d < 4; ++d) {                              \
      int o = (d + rotc) & 3;                                                    \
      int row = n0s + o;                                                         \
      bf16x4 vv = (o & 2) ? ((o & 1) ? R3 : R2) : ((o & 1) ? R1 : R0);           \
      *(bf16x4*)(ldsc + (OB) + 32768 + row * 128 +                               \
                 ((((k4 >> 3) ^ (row & 7)) << 4) | ((k4 & 7) << 1))) = vv;       \
    }                                                                            \
  }
#define LOAD_A(BB, MH)                                                     \
  _Pragma("unroll") for (int m = 0; m < 4; ++m) {                          \
    a[m * 2 + 0] = *(const v8bf*)(ldsc + (BB) + abase + (MH) * 8192 + m * 2048 + acol0); \
    a[m * 2 + 1] = *(const v8bf*)(ldsc + (BB) + abase + (MH) * 8192 + m * 2048 + acol1); \
  }
#define LOAD_B(BB, NH, BR)                                                 \
  _Pragma("unroll") for (int n = 0; n < 2; ++n) {                          \
    BR[n * 2 + 0] = *(const v8bf*)(ldsc + (BB) + bbase + (NH) * 4096 + n * 2048 + acol0); \
    BR[n * 2 + 1] = *(const v8bf*)(ldsc + (BB) + bbase + (NH) * 4096 + n * 2048 + acol1); \
  }
#define MFMA_QUAD(MH, NH, BR)                                              \
  _Pragma("unroll") for (int m = 0; m < 4; ++m) {                          \
    _Pragma("unroll") for (int n = 0; n < 2; ++n) {                        \
      acc[(MH) * 4 + m][(NH) * 2 + n] = __builtin_amdgcn_mfma_f32_16x16x32_bf16( \
          a[m * 2 + 0], BR[n * 2 + 0], acc[(MH) * 4 + m][(NH) * 2 + n], 0, 0, 0); \
      acc[(MH) * 4 + m][(NH) * 2 + n] = __builtin_amdgcn_mfma_f32_16x16x32_bf16( \
          a[m * 2 + 1], BR[n * 2 + 1], acc[(MH) * 4 + m][(NH) * 2 + n], 0, 0, 0); \
    }                                                                      \
  }

  const int NT = K >> 6;

  // ---- prologue: tile 0 fully staged into buf0; L holds B(t1) ----
  STAGE_A(0);
  LOAD_BGLB();              // L = B(t0)
  gAp += 64;                // -> A(t1)
  CVT_WRITE_B(0);           // waits own gloads (prologue only)
  if (NT > 1) gB += (size_t)64 * ldnB;   // -> t1
  LOAD_BGLB();              // L = B(t1)
  if (NT > 2) gB += (size_t)64 * ldnB;   // -> t2
  asm volatile("s_waitcnt vmcnt(8) lgkmcnt(0)" ::: "memory");  // A(t0)+writes done
  __builtin_amdgcn_s_barrier();

  int buf = 0;
  for (int tt = 0; tt < NT; ++tt) {
    const int bb = buf << 16;
    const int ob = (buf ^ 1) << 16;
    const bool pf = (tt + 1 < NT);

    // issue block: next-tile B write (consumes L, full-tile cover), next-tile
    // A stage, B(t+2) gloads (always issued, clamped ptr -> wait invariant).
    if (pf) {
      CVT_WRITE_B(ob);
      STAGE_A(ob);
      gAp += 64;
    }
    LOAD_BGLB();
    if (tt + 3 < NT) gB += (size_t)64 * ldnB;
    __builtin_amdgcn_sched_barrier(0);

    // compute region: compiler interleaves ds_reads + MFMA freely
    {
      v8bf a[8], b0r[4], b1r[4];
      LOAD_A(bb, 0);
      LOAD_B(bb, 0, b0r);
      MFMA_QUAD(0, 0, b0r);
      LOAD_B(bb, 1, b1r);
      MFMA_QUAD(0, 1, b1r);
      LOAD_A(bb, 1);
      MFMA_QUAD(1, 1, b1r);
      LOAD_B(bb, 0, b0r);
      MFMA_QUAD(1, 0, b0r);
    }
    __builtin_amdgcn_sched_barrier(0);

    // exit: drain A-stages + all ds ops; leave the 8 B-gloads in flight.
    asm volatile("s_waitcnt vmcnt(8) lgkmcnt(0)" ::: "memory");
    __builtin_amdgcn_s_barrier();
    buf ^= 1;
  }

  float* Cp = (float*)Cout + (SPLITK ? (size_t)bz * M * N : 0);
#pragma unroll
  for (int mi = 0; mi < 8; ++mi) {
    int grow = m0 + wr * 128 + mi * 16 + kc * 4;
#pragma unroll
    for (int nj = 0; nj < 4; ++nj) {
      int gcol = n0 + wn * 64 + nj * 16 + r16;
      float bv = SPLITK ? 0.f : bias[gcol];
#pragma unroll
      for (int j = 0; j < 4; ++j) {
        float v = acc[mi][nj][j] + bv;
        size_t idxo = (size_t)(grow + j) * N + gcol;
        if (OUT_BF16)
          ((unsigned short*)Cout)[idxo] = f2bf(v);
        else
          Cp[idxo] = v;
      }
    }
  }
#undef STAGE_A
#undef LOAD_BGLB
#undef CVT_WRITE_B
#undef LOAD_A
#undef LOAD_B
#undef MFMA_QUAD
}

// out[i] = sum_s part[s*MN + i] + bias[i % N], 4 elems/thread, fixed order
__global__ void reduce_splitk_kernel(const float* __restrict__ part,
                                     const float* __restrict__ bias,
                                     float* __restrict__ out, int MN, int N, int S) {
  int i = (blockIdx.x * 256 + threadIdx.x) * 4;
  float4 s = *(const float4*)(part + i);
  for (int k = 1; k < S; ++k) {
    float4 v = *(const float4*)(part + (size_t)k * MN + i);
    s.x += v.x; s.y += v.y; s.z += v.z; s.w += v.w;
  }
  int n = i & (N - 1);
  const float4 bv = *(const float4*)(bias + n);
  s.x += bv.x; s.y += bv.y; s.z += bv.z; s.w += bv.w;
  *(float4*)(out + i) = s;
}

// ---------------- launch ----------------

extern "C" void kernel_launch(void* const* d_in, const int* in_sizes, int n_in,
                              void* d_out, int out_size, void* d_ws, size_t ws_size,
                              hipStream_t stream) {
  const float* x     = (const float*)d_in[0];   // 1024 x 4096
  const float* W_in  = (const float*)d_in[1];   // 4096 x 16384
  const float* b_in  = (const float*)d_in[2];   // 16384
  const float* W_e   = (const float*)d_in[3];   // 8 x 8
  const float* W_out = (const float*)d_in[4];   // 16384 x 2048
  const float* b_out = (const float*)d_in[5];   // 2048
  float* out = (float*)d_out;                   // 1024 x 2048 f32

  char* ws = (char*)d_ws;
  const size_t OFF_M3 = 0;                      // 256 B
  const size_t OFF_X  = 1ull << 20;             // 8 MB   (x bf16)
  const size_t OFF_H  = 10ull << 20;            // 32 MB  (h bf16)
  const size_t OFF_P  = 48ull << 20;            // 64 MB  split-K partials
  float* m3          = (float*)(ws + OFF_M3);
  unsigned short* xb = (unsigned short*)(ws + OFF_X);
  unsigned short* h  = (unsigned short*)(ws + OFF_H);
  float* part        = (float*)(ws + OFF_P);

  prep_m3_kernel<<<1, 64, 0, stream>>>(W_e, m3);
  cvt_bf16_kernel<<<2048, 256, 0, stream>>>(x, xb);  // 1024*4096 / (256*8)

  // h_pre = x @ W_in + b_in   (1024 x 16384, bf16 out; W staged f32->bf16 in-kernel)
  gemm256f_kernel<true, false><<<dim3(64, 4), 512, 0, stream>>>(
      xb, W_in, b_in, h, 1024, 16384, 4096, 4096, 16384);

  // h = h_pre * (I (x) M^3)  (in-place blade fold)
  fold_h_kernel<<<8192, 256, 0, stream>>>(h, m3);

  // partials[z] = h @ W_out over K-chunk z  (split-K 8 x 2048)
  gemm256f_kernel<false, true><<<dim3(8, 4, 8), 512, 0, stream>>>(
      h, W_out, nullptr, part, 1024, 2048, 2048, 16384, 2048);

  // out = sum_z partials[z] + b_out
  reduce_splitk_kernel<<<2048, 256, 0, stream>>>(part, b_out, out, 1024 * 2048, 2048, 8);
}